// Round 11
// baseline (22927.563 us; speedup 1.0000x reference)
//
#include <hip/hip_runtime.h>
#include <cstddef>
#include <cstdint>

// Problem constants
#define BDIM  1024        // batch rows
#define DM    512         // embedding dim
#define CREAL 10000       // dictionary atoms
#define CP    10112       // padded atoms = 79*128 = 158*64 = 316*32
#define KSPL  16          // split-K chunks for GEMM1 (atomic accumulation)
#define RHOC  5.0f
#define THRC  (0.01f/5.0f)
#define NIT   100
#define NSIT  12

typedef float f32x4 __attribute__((ext_vector_type(4)));
typedef _Float16 f16x8 __attribute__((ext_vector_type(8)));

// ---------------- helpers ----------------

// Split scheme: x ~ h + l/64, h = fp16(x), l = fp16((x-h)*64)  (pair error ~2^-24 rel).
// GEMM terms: h*h + (h*2^-6)*l_B + l_A*(h*2^-6)  — dropped l*l term ~2^-24 rel.
__device__ __forceinline__ f16x8 scl6(f16x8 v) {
    f16x8 r;
#pragma unroll
    for (int i = 0; i < 8; i++) r[i] = v[i] * (_Float16)0.015625f;  // exact exponent shift
    return r;
}

__device__ __forceinline__ float blk_sum256(float v) {
    __shared__ float sb[4];
#pragma unroll
    for (int o = 32; o; o >>= 1) v += __shfl_down(v, o, 64);
    int lane = threadIdx.x & 63, w = threadIdx.x >> 6;
    __syncthreads();
    if (lane == 0) sb[w] = v;
    __syncthreads();
    return sb[0] + sb[1] + sb[2] + sb[3];
}

// txt = normalize(text) per row
__global__ __launch_bounds__(256) void knorm_rows(const float* __restrict__ X,
                                                  float* __restrict__ out) {
    int row = blockIdx.x, t = threadIdx.x;
    int off = row * DM + t * 2;
    float2 v = *(const float2*)(X + off);
    float ss = blk_sum256(v.x * v.x + v.y * v.y);
    float inv = 1.0f / fmaxf(sqrtf(ss), 1e-12f);
    float2 o = {v.x * inv, v.y * inv};
    *(float2*)(out + off) = o;
}

// Y = normalize(normalize(image) - mean) per row
__global__ __launch_bounds__(256) void kprep_Y(const float* __restrict__ img,
                                               const float* __restrict__ mean,
                                               float* __restrict__ Y) {
    int row = blockIdx.x, t = threadIdx.x;
    int off = row * DM + t * 2;
    float2 v = *(const float2*)(img + off);
    float ss = blk_sum256(v.x * v.x + v.y * v.y);
    float inv = 1.0f / fmaxf(sqrtf(ss), 1e-12f);
    float2 mm = *(const float2*)(mean + t * 2);
    float tx = v.x * inv - mm.x, ty = v.y * inv - mm.y;
    float ss2 = blk_sum256(tx * tx + ty * ty);
    float inv2 = 1.0f / fmaxf(sqrtf(ss2), 1e-12f);
    float2 o = {tx * inv2, ty * inv2};
    *(float2*)(Y + off) = o;
}

// transpose (+zero-pad rows>=Rvalid), split to fp16 h/l pair (l stored *64) and write
// the fp16 planes in MFMA FRAGMENT-SWIZZLED order:
//   plane idx = (rowtile16 * (ncols/32) + coltile32)*512 + (kquad*16 + row&15)*8 + (col&7)
// so a wave's fragment load is base + lane*8 (fully coalesced, no LDS needed).
// optional fp32 out = reconstructed pair (h + l/64), ROW-MAJOR.
__global__ __launch_bounds__(256) void ktrs(const float* __restrict__ in,
                                            float* __restrict__ out32,
                                            _Float16* __restrict__ oH,
                                            _Float16* __restrict__ oL,
                                            int Rvalid, int Cin, int Rout) {
    __shared__ float tile[64][65];
    int r0 = blockIdx.x * 64;   // rows of in  (cols of out)
    int c0 = blockIdx.y * 64;   // cols of in  (rows of out)
    int t = threadIdx.x;
    int ri = r0 + (t >> 2);
    int cc = (t & 3) * 16;
#pragma unroll
    for (int q = 0; q < 4; ++q) {
        float4 v = {0.f, 0.f, 0.f, 0.f};
        if (ri < Rvalid) v = *(const float4*)(in + (size_t)ri * Cin + c0 + cc + q * 4);
        *(float4*)&tile[t >> 2][cc + q * 4] = v;
    }
    __syncthreads();
    int oc = c0 + (t >> 2);            // out row
    int orr = r0 + (t & 3) * 16;       // out col base (multiple of 16)
    _Float16 hv[16], lv[16];
#pragma unroll
    for (int q = 0; q < 16; ++q) {
        float v = tile[(t & 3) * 16 + q][t >> 2];
        _Float16 h = (_Float16)v;
        _Float16 l = (_Float16)((v - (float)h) * 64.f);
        hv[q] = h; lv[q] = l;
        if (out32) out32[(size_t)oc * Rout + orr + q] = (float)h + (float)l * 0.015625f;
    }
    int rt = oc >> 4, rin = oc & 15;
    int kt = orr >> 5;
    int kq0 = (orr >> 3) & 3;          // 0 or 2
    size_t base = ((size_t)rt * (Rout >> 5) + kt) * 512;
    *(f16x8*)(oH + base + (size_t)(kq0 * 16 + rin) * 8)       = *(f16x8*)&hv[0];
    *(f16x8*)(oH + base + (size_t)((kq0 + 1) * 16 + rin) * 8) = *(f16x8*)&hv[8];
    *(f16x8*)(oL + base + (size_t)(kq0 * 16 + rin) * 8)       = *(f16x8*)&lv[0];
    *(f16x8*)(oL + base + (size_t)((kq0 + 1) * 16 + rin) * 8) = *(f16x8*)&lv[8];
}

// G = Dt*Dt^T + rho I  (Dt [512][CP] fp32; 64x64 tiles, K=CP)
__global__ __launch_bounds__(256) void kG(const float* __restrict__ Dt,
                                          float* __restrict__ G) {
    __shared__ float As[32][68];
    __shared__ float Bs[32][68];
    int tid = threadIdx.x;
    int j0 = blockIdx.x * 64, i0 = blockIdx.y * 64;
    int tn = (tid & 15) * 4, tm = (tid >> 4) * 4;
    float acc[4][4];
#pragma unroll
    for (int i = 0; i < 4; i++)
#pragma unroll
        for (int j = 0; j < 4; j++) acc[i][j] = 0.f;
    for (int k0 = 0; k0 < CP; k0 += 32) {
        __syncthreads();
#pragma unroll
        for (int p = 0; p < 2; ++p) {
            int idx = tid + p * 256;
            int row = idx >> 3, kv = (idx & 7) << 2;
            float4 va = *(const float4*)(Dt + (size_t)(i0 + row) * CP + k0 + kv);
            As[kv + 0][row] = va.x; As[kv + 1][row] = va.y;
            As[kv + 2][row] = va.z; As[kv + 3][row] = va.w;
            float4 vb = *(const float4*)(Dt + (size_t)(j0 + row) * CP + k0 + kv);
            Bs[kv + 0][row] = vb.x; Bs[kv + 1][row] = vb.y;
            Bs[kv + 2][row] = vb.z; Bs[kv + 3][row] = vb.w;
        }
        __syncthreads();
#pragma unroll
        for (int k = 0; k < 32; ++k) {
            float4 a4 = *(const float4*)&As[k][tm];
            float4 b4 = *(const float4*)&Bs[k][tn];
            float af[4] = {a4.x, a4.y, a4.z, a4.w};
            float bf[4] = {b4.x, b4.y, b4.z, b4.w};
#pragma unroll
            for (int i = 0; i < 4; i++)
#pragma unroll
                for (int j = 0; j < 4; j++) acc[i][j] = fmaf(af[i], bf[j], acc[i][j]);
        }
    }
#pragma unroll
    for (int i = 0; i < 4; i++)
#pragma unroll
        for (int j = 0; j < 4; j++) {
            int gi = i0 + tm + i, gj = j0 + tn + j;
            G[gi * DM + gj] = acc[i][j] + ((gi == gj) ? RHOC : 0.f);
        }
}

__global__ void krow_abssum(const float* __restrict__ G, float* __restrict__ gmax) {
    int row = blockIdx.x, t = threadIdx.x;   // 64 threads = 1 wave
    float s = 0.f;
    for (int j = t; j < DM; j += 64) s += fabsf(G[row * DM + j]);
#pragma unroll
    for (int o = 32; o; o >>= 1) s += __shfl_down(s, o, 64);
    if (t == 0) atomicMax((int*)gmax, __float_as_int(s));
}

__global__ void kinit_X0(const float* __restrict__ gmax, float* __restrict__ X) {
    int idx = blockIdx.x * 256 + threadIdx.x;
    int i = idx >> 9, j = idx & 511;
    X[idx] = (i == j) ? (1.0f / gmax[0]) : 0.0f;
}

// T = G @ X (512^3 NN, 64x64 tiles)
__global__ __launch_bounds__(256) void kgemm_ns_T(const float* __restrict__ G,
                                                  const float* __restrict__ X,
                                                  float* __restrict__ T) {
    __shared__ float As[32][68];
    __shared__ float Bs[32][68];
    int tid = threadIdx.x;
    int n0 = blockIdx.x * 64, m0 = blockIdx.y * 64;
    int tn = (tid & 15) * 4, tm = (tid >> 4) * 4;
    float acc[4][4];
#pragma unroll
    for (int i = 0; i < 4; i++)
#pragma unroll
        for (int j = 0; j < 4; j++) acc[i][j] = 0.f;
    for (int k0 = 0; k0 < DM; k0 += 32) {
        __syncthreads();
#pragma unroll
        for (int p = 0; p < 2; ++p) {
            int idx = tid + p * 256;
            {
                int row = idx >> 3, kv = (idx & 7) << 2;
                float4 v = *(const float4*)(G + (m0 + row) * DM + k0 + kv);
                As[kv + 0][row] = v.x; As[kv + 1][row] = v.y;
                As[kv + 2][row] = v.z; As[kv + 3][row] = v.w;
            }
            {
                int r = idx >> 4, cv = (idx & 15) << 2;
                *(float4*)&Bs[r][cv] = *(const float4*)(X + (k0 + r) * DM + n0 + cv);
            }
        }
        __syncthreads();
#pragma unroll
        for (int k = 0; k < 32; ++k) {
            float4 a4 = *(const float4*)&As[k][tm];
            float4 b4 = *(const float4*)&Bs[k][tn];
            float af[4] = {a4.x, a4.y, a4.z, a4.w};
            float bf[4] = {b4.x, b4.y, b4.z, b4.w};
#pragma unroll
            for (int i = 0; i < 4; i++)
#pragma unroll
                for (int j = 0; j < 4; j++) acc[i][j] = fmaf(af[i], bf[j], acc[i][j]);
        }
    }
#pragma unroll
    for (int i = 0; i < 4; i++) {
        float4 o = {acc[i][0], acc[i][1], acc[i][2], acc[i][3]};
        *(float4*)(T + (m0 + tm + i) * DM + n0 + tn) = o;
    }
}

// Xn = 2*Xo - Xo @ T
__global__ __launch_bounds__(256) void kgemm_ns_X(const float* __restrict__ Xo,
                                                  const float* __restrict__ T,
                                                  float* __restrict__ Xn) {
    __shared__ float As[32][68];
    __shared__ float Bs[32][68];
    int tid = threadIdx.x;
    int n0 = blockIdx.x * 64, m0 = blockIdx.y * 64;
    int tn = (tid & 15) * 4, tm = (tid >> 4) * 4;
    float acc[4][4];
#pragma unroll
    for (int i = 0; i < 4; i++)
#pragma unroll
        for (int j = 0; j < 4; j++) acc[i][j] = 0.f;
    for (int k0 = 0; k0 < DM; k0 += 32) {
        __syncthreads();
#pragma unroll
        for (int p = 0; p < 2; ++p) {
            int idx = tid + p * 256;
            {
                int row = idx >> 3, kv = (idx & 7) << 2;
                float4 v = *(const float4*)(Xo + (m0 + row) * DM + k0 + kv);
                As[kv + 0][row] = v.x; As[kv + 1][row] = v.y;
                As[kv + 2][row] = v.z; As[kv + 3][row] = v.w;
            }
            {
                int r = idx >> 4, cv = (idx & 15) << 2;
                *(float4*)&Bs[r][cv] = *(const float4*)(T + (k0 + r) * DM + n0 + cv);
            }
        }
        __syncthreads();
#pragma unroll
        for (int k = 0; k < 32; ++k) {
            float4 a4 = *(const float4*)&As[k][tm];
            float4 b4 = *(const float4*)&Bs[k][tn];
            float af[4] = {a4.x, a4.y, a4.z, a4.w};
            float bf[4] = {b4.x, b4.y, b4.z, b4.w};
#pragma unroll
            for (int i = 0; i < 4; i++)
#pragma unroll
                for (int j = 0; j < 4; j++) acc[i][j] = fmaf(af[i], bf[j], acc[i][j]);
        }
    }
#pragma unroll
    for (int i = 0; i < 4; i++) {
        int base = (m0 + tm + i) * DM + n0 + tn;
        float4 xo = *(const float4*)(Xo + base);
        float4 o = {2.f * xo.x - acc[i][0], 2.f * xo.y - acc[i][1],
                    2.f * xo.z - acc[i][2], 2.f * xo.w - acc[i][3]};
        *(float4*)(Xn + base) = o;
    }
}

// NN fp32: out[M][CP] = A[M][512] @ B[512][CP]
// MODE 0: store fp32. MODE 1: store a = acc*0.2 as fp16 scaled by 64.
template <int MODE>
__global__ __launch_bounds__(256) void kgemm_nn64(const float* __restrict__ A,
                                                  const float* __restrict__ B,
                                                  float* __restrict__ out32,
                                                  _Float16* __restrict__ oA) {
    __shared__ float As[32][68];
    __shared__ float Bs[32][68];
    int tid = threadIdx.x;
    int n0 = blockIdx.x * 64, m0 = blockIdx.y * 64;
    int tn = (tid & 15) * 4, tm = (tid >> 4) * 4;
    float acc[4][4];
#pragma unroll
    for (int i = 0; i < 4; i++)
#pragma unroll
        for (int j = 0; j < 4; j++) acc[i][j] = 0.f;
    for (int k0 = 0; k0 < DM; k0 += 32) {
        __syncthreads();
#pragma unroll
        for (int p = 0; p < 2; ++p) {
            int idx = tid + p * 256;
            {
                int row = idx >> 3, kv = (idx & 7) << 2;
                float4 v = *(const float4*)(A + (size_t)(m0 + row) * DM + k0 + kv);
                As[kv + 0][row] = v.x; As[kv + 1][row] = v.y;
                As[kv + 2][row] = v.z; As[kv + 3][row] = v.w;
            }
            {
                int r = idx >> 4, cv = (idx & 15) << 2;
                *(float4*)&Bs[r][cv] = *(const float4*)(B + (size_t)(k0 + r) * CP + n0 + cv);
            }
        }
        __syncthreads();
#pragma unroll
        for (int k = 0; k < 32; ++k) {
            float4 a4 = *(const float4*)&As[k][tm];
            float4 b4 = *(const float4*)&Bs[k][tn];
            float af[4] = {a4.x, a4.y, a4.z, a4.w};
            float bf[4] = {b4.x, b4.y, b4.z, b4.w};
#pragma unroll
            for (int i = 0; i < 4; i++)
#pragma unroll
                for (int j = 0; j < 4; j++) acc[i][j] = fmaf(af[i], bf[j], acc[i][j]);
        }
    }
#pragma unroll
    for (int i = 0; i < 4; i++)
#pragma unroll
        for (int j = 0; j < 4; j++) {
            size_t idx = (size_t)(m0 + tm + i) * CP + n0 + tn + j;
            if (MODE == 0) out32[idx] = acc[i][j];
            else           oA[idx] = (_Float16)(acc[i][j] * 0.2f * 64.f);
        }
}

// aD = Y@G/rho - Y   (out [1024][512]; 64x64 tiles, K=512)
__global__ __launch_bounds__(256) void kgemm_aD(const float* __restrict__ Yb,
                                                const float* __restrict__ G,
                                                float* __restrict__ aD) {
    __shared__ float As[32][68];
    __shared__ float Bs[32][68];
    int tid = threadIdx.x;
    int n0 = blockIdx.x * 64, m0 = blockIdx.y * 64;
    int tn = (tid & 15) * 4, tm = (tid >> 4) * 4;
    float acc[4][4];
#pragma unroll
    for (int i = 0; i < 4; i++)
#pragma unroll
        for (int j = 0; j < 4; j++) acc[i][j] = 0.f;
    for (int k0 = 0; k0 < DM; k0 += 32) {
        __syncthreads();
#pragma unroll
        for (int p = 0; p < 2; ++p) {
            int idx = tid + p * 256;
            {
                int row = idx >> 3, kv = (idx & 7) << 2;
                float4 v = *(const float4*)(Yb + (size_t)(m0 + row) * DM + k0 + kv);
                As[kv + 0][row] = v.x; As[kv + 1][row] = v.y;
                As[kv + 2][row] = v.z; As[kv + 3][row] = v.w;
            }
            {
                int r = idx >> 4, cv = (idx & 15) << 2;
                *(float4*)&Bs[r][cv] = *(const float4*)(G + (k0 + r) * DM + n0 + cv);
            }
        }
        __syncthreads();
#pragma unroll
        for (int k = 0; k < 32; ++k) {
            float4 a4 = *(const float4*)&As[k][tm];
            float4 b4 = *(const float4*)&Bs[k][tn];
            float af[4] = {a4.x, a4.y, a4.z, a4.w};
            float bf[4] = {b4.x, b4.y, b4.z, b4.w};
#pragma unroll
            for (int i = 0; i < 4; i++)
#pragma unroll
                for (int j = 0; j < 4; j++) acc[i][j] = fmaf(af[i], bf[j], acc[i][j]);
        }
    }
#pragma unroll
    for (int i = 0; i < 4; i++) {
        int base = (m0 + tm + i) * DM + n0 + tn;
        float4 y4 = *(const float4*)(Yb + base);
        float4 o = {acc[i][0] * 0.2f - y4.x, acc[i][1] * 0.2f - y4.y,
                    acc[i][2] * 0.2f - y4.z, acc[i][3] * 0.2f - y4.w};
        *(float4*)(aD + base) = o;
    }
}

// ---------------- MFMA fp16-pair GEMMs ----------------
// A-frag: A[m=lane&15][k=(lane>>4)*8+j]; B-frag mirrored; C/D: col=lane&15, row=(lane>>4)*4+reg.

// OLD-PATH kg1 (fallback + final z@Dp): P fp32 input, LDS A-build.
// MODE 0: v = (P>thr)? P-2thr : -P ;  MODE 1: v = relu(P-thr)
template <int MODE>
__global__ __launch_bounds__(256) void kg1p(const float* __restrict__ Pst,
                                            const _Float16* __restrict__ DHs,
                                            const _Float16* __restrict__ DLs,
                                            const float* __restrict__ aD,
                                            float* __restrict__ Qf) {
    __shared__ _Float16 sA[2][2][128 * 32];
    const int id = blockIdx.x;
    const int g  = id & 63;
    const int mb = id >> 6;
    const int nb = g & 3;
    const int ks = g >> 2;
    const int n0 = nb * 128;
    const int m0 = mb * 128;
    const int tid = threadIdx.x;
    const int lane = tid & 63;
    const int wvu = tid >> 6;
    const int wm = (wvu >> 1) * 64, wn = (wvu & 1) * 64;
    const int arow = tid >> 1;
    const int aq = (tid & 1) * 16;
    const int quad = (lane >> 4) * 8;
    f32x4 acc[4][4] = {};

    const int steps = CP / 32;
    const int per = (steps + KSPL - 1) / KSPL;
    int s0 = ks * per;
    int s1 = s0 + per; if (s1 > steps) s1 = steps;

    float pv[16];
    {
        size_t go = (size_t)(m0 + arow) * CP + s0 * 32 + aq;
        *(float4*)&pv[0]  = *(const float4*)(Pst + go);
        *(float4*)&pv[4]  = *(const float4*)(Pst + go + 4);
        *(float4*)&pv[8]  = *(const float4*)(Pst + go + 8);
        *(float4*)&pv[12] = *(const float4*)(Pst + go + 12);
    }
    const int ntb = (n0 + wn) >> 4;

    for (int sp = s0; sp < s1; ++sp) {
        const int buf = (sp - s0) & 1;
        {
            _Float16 th[16], tl[16];
#pragma unroll
            for (int e = 0; e < 16; ++e) {
                float p = pv[e];
                float v = (MODE == 0) ? ((p > THRC) ? p - 2.f * THRC : -p)
                                      : fmaxf(p - THRC, 0.f);
                _Float16 h = (_Float16)v;
                th[e] = h;
                tl[e] = (_Float16)((v - (float)h) * 64.f);
            }
            int lb = arow * 32 + aq;
            *(f16x8*)&sA[buf][0][lb]     = *(f16x8*)&th[0];
            *(f16x8*)&sA[buf][0][lb + 8] = *(f16x8*)&th[8];
            *(f16x8*)&sA[buf][1][lb]     = *(f16x8*)&tl[0];
            *(f16x8*)&sA[buf][1][lb + 8] = *(f16x8*)&tl[8];
        }
        if (sp + 1 < s1) {
            size_t go = (size_t)(m0 + arow) * CP + (sp + 1) * 32 + aq;
            *(float4*)&pv[0]  = *(const float4*)(Pst + go);
            *(float4*)&pv[4]  = *(const float4*)(Pst + go + 4);
            *(float4*)&pv[8]  = *(const float4*)(Pst + go + 8);
            *(float4*)&pv[12] = *(const float4*)(Pst + go + 12);
        }
        f16x8 bfh[4], bfl[4], bfs[4];
#pragma unroll
        for (int j = 0; j < 4; j++) {
            size_t go = ((size_t)(ntb + j) * (CP / 32) + sp) * 512 + (size_t)lane * 8;
            bfh[j] = *(const f16x8*)(DHs + go);
            bfl[j] = *(const f16x8*)(DLs + go);
        }
        __syncthreads();
        f16x8 af[2][4], afs[4];
#pragma unroll
        for (int i = 0; i < 4; i++) {
            int ro = (wm + i * 16 + (lane & 15)) * 32 + quad;
            af[0][i] = *(const f16x8*)&sA[buf][0][ro];
            af[1][i] = *(const f16x8*)&sA[buf][1][ro];
            afs[i] = scl6(af[0][i]);
        }
#pragma unroll
        for (int j = 0; j < 4; j++) bfs[j] = scl6(bfh[j]);
#pragma unroll
        for (int i = 0; i < 4; i++)
#pragma unroll
            for (int j = 0; j < 4; j++) {
                acc[i][j] = __builtin_amdgcn_mfma_f32_16x16x32_f16(af[0][i], bfh[j], acc[i][j], 0, 0, 0);
                acc[i][j] = __builtin_amdgcn_mfma_f32_16x16x32_f16(afs[i],   bfl[j], acc[i][j], 0, 0, 0);
                acc[i][j] = __builtin_amdgcn_mfma_f32_16x16x32_f16(af[1][i], bfs[j], acc[i][j], 0, 0, 0);
            }
    }
    const int r0 = (lane >> 4) * 4, c0l = lane & 15;
#pragma unroll
    for (int i = 0; i < 4; i++)
#pragma unroll
        for (int v = 0; v < 4; v++) {
            int row = m0 + wm + i * 16 + r0 + v;
#pragma unroll
            for (int j = 0; j < 4; j++) {
                size_t oi = (size_t)row * DM + n0 + wn + j * 16 + c0l;
                float base = (MODE == 0 && ks == 0) ? aD[oi] : 0.f;
                atomicAdd(&Qf[oi], acc[i][j][v] + base);
            }
        }
}

// FAST kg1: A from pre-split pre-swizzled S planes. No LDS, no barrier.
__global__ __launch_bounds__(256) void kg1s(const _Float16* __restrict__ SH,
                                            const _Float16* __restrict__ SL,
                                            const _Float16* __restrict__ DHs,
                                            const _Float16* __restrict__ DLs,
                                            const float* __restrict__ aD,
                                            float* __restrict__ Qf) {
    const int id = blockIdx.x;
    const int g  = id & 63;
    const int mb = id >> 6;
    const int nb = g & 3;
    const int ks = g >> 2;
    const int n0 = nb * 128;
    const int m0 = mb * 128;
    const int tid = threadIdx.x;
    const int lane = tid & 63;
    const int wvu = tid >> 6;
    const int wm = (wvu >> 1) * 64, wn = (wvu & 1) * 64;
    f32x4 acc[4][4] = {};

    const int steps = CP / 32;
    const int per = (steps + KSPL - 1) / KSPL;
    int s0 = ks * per;
    int s1 = s0 + per; if (s1 > steps) s1 = steps;

    const int mtb = (m0 + wm) >> 4;
    const int ntb = (n0 + wn) >> 4;

    for (int sp = s0; sp < s1; ++sp) {
        f16x8 ah[4], al[4], bh[4], bl[4];
#pragma unroll
        for (int i = 0; i < 4; i++) {
            size_t go = ((size_t)(mtb + i) * (CP / 32) + sp) * 512 + (size_t)lane * 8;
            ah[i] = *(const f16x8*)(SH + go);
            al[i] = *(const f16x8*)(SL + go);
        }
#pragma unroll
        for (int j = 0; j < 4; j++) {
            size_t go = ((size_t)(ntb + j) * (CP / 32) + sp) * 512 + (size_t)lane * 8;
            bh[j] = *(const f16x8*)(DHs + go);
            bl[j] = *(const f16x8*)(DLs + go);
        }
        f16x8 as_[4], bs_[4];
#pragma unroll
        for (int i = 0; i < 4; i++) as_[i] = scl6(ah[i]);
#pragma unroll
        for (int j = 0; j < 4; j++) bs_[j] = scl6(bh[j]);
#pragma unroll
        for (int i = 0; i < 4; i++)
#pragma unroll
            for (int j = 0; j < 4; j++) {
                acc[i][j] = __builtin_amdgcn_mfma_f32_16x16x32_f16(ah[i],  bh[j],  acc[i][j], 0, 0, 0);
                acc[i][j] = __builtin_amdgcn_mfma_f32_16x16x32_f16(as_[i], bl[j],  acc[i][j], 0, 0, 0);
                acc[i][j] = __builtin_amdgcn_mfma_f32_16x16x32_f16(al[i],  bs_[j], acc[i][j], 0, 0, 0);
            }
    }
    const int r0 = (lane >> 4) * 4, c0l = lane & 15;
#pragma unroll
    for (int i = 0; i < 4; i++)
#pragma unroll
        for (int v = 0; v < 4; v++) {
            int row = m0 + wm + i * 16 + r0 + v;
#pragma unroll
            for (int j = 0; j < 4; j++) {
                size_t oi = (size_t)row * DM + n0 + wn + j * 16 + c0l;
                float base = (ks == 0) ? aD[oi] : 0.f;
                atomicAdd(&Qf[oi], acc[i][j][v] + base);
            }
        }
}

// Qf (fp32 [1024][512]) -> swizzled fp16 pair (kg2 A-layout, ktile over DM/32)
__global__ void kredQ(const float* __restrict__ Qf,
                      _Float16* __restrict__ QH, _Float16* __restrict__ QL) {
    int gidx = blockIdx.x * 256 + threadIdx.x;   // 65536 groups of 8
    int row = gidx >> 6;
    int kb = (gidx & 63) * 8;
    float v8[8];
    *(float4*)&v8[0] = *(const float4*)(Qf + (size_t)row * DM + kb);
    *(float4*)&v8[4] = *(const float4*)(Qf + (size_t)row * DM + kb + 4);
    _Float16 h8[8], l8[8];
#pragma unroll
    for (int e = 0; e < 8; e++) {
        _Float16 h = (_Float16)v8[e];
        h8[e] = h;
        l8[e] = (_Float16)((v8[e] - (float)h) * 64.f);
    }
    size_t o = ((size_t)(row >> 4) * (DM / 32) + (kb >> 5)) * 512
             + (size_t)(((kb >> 3) & 3) * 16 + (row & 15)) * 8;
    *(f16x8*)(QH + o) = *(f16x8*)&h8[0];
    *(f16x8*)(QL + o) = *(f16x8*)&l8[0];
}

// OLD-PATH kg2 (fallback): Qf fp32 input, LDS A-build; epilogue P only.
__global__ __launch_bounds__(256) void kg2o(const float* __restrict__ Qf,
                                            const _Float16* __restrict__ EHs,
                                            const _Float16* __restrict__ ELs,
                                            const _Float16* __restrict__ AH,
                                            float* __restrict__ Pst) {
    __shared__ _Float16 sA[2][2][128 * 32];
    const int id = blockIdx.x;
    const int nb = id % 80;
    const int mb = id / 80;
    if (nb >= 79) return;
    const int n0 = nb * 128;
    const int m0 = mb * 128;
    const int tid = threadIdx.x;
    const int lane = tid & 63;
    const int wvu = tid >> 6;
    const int wm = (wvu >> 1) * 64, wn = (wvu & 1) * 64;
    const int arow = tid >> 1;
    const int aq = (tid & 1) * 16;
    const int quad = (lane >> 4) * 8;
    f32x4 acc[4][4] = {};

    float qv[16];
    {
        size_t go = (size_t)(m0 + arow) * DM + aq;
        *(float4*)&qv[0]  = *(const float4*)(Qf + go);
        *(float4*)&qv[4]  = *(const float4*)(Qf + go + 4);
        *(float4*)&qv[8]  = *(const float4*)(Qf + go + 8);
        *(float4*)&qv[12] = *(const float4*)(Qf + go + 12);
    }
    const int ntb = (n0 + wn) >> 4;

    for (int kk = 0; kk < DM / 32; ++kk) {
        const int buf = kk & 1;
        {
            _Float16 th[16], tl[16];
#pragma unroll
            for (int e = 0; e < 16; ++e) {
                float v = qv[e];
                _Float16 h = (_Float16)v;
                th[e] = h;
                tl[e] = (_Float16)((v - (float)h) * 64.f);
            }
            int lb = arow * 32 + aq;
            *(f16x8*)&sA[buf][0][lb]     = *(f16x8*)&th[0];
            *(f16x8*)&sA[buf][0][lb + 8] = *(f16x8*)&th[8];
            *(f16x8*)&sA[buf][1][lb]     = *(f16x8*)&tl[0];
            *(f16x8*)&sA[buf][1][lb + 8] = *(f16x8*)&tl[8];
        }
        if (kk + 1 < DM / 32) {
            size_t go = (size_t)(m0 + arow) * DM + (kk + 1) * 32 + aq;
            *(float4*)&qv[0]  = *(const float4*)(Qf + go);
            *(float4*)&qv[4]  = *(const float4*)(Qf + go + 4);
            *(float4*)&qv[8]  = *(const float4*)(Qf + go + 8);
            *(float4*)&qv[12] = *(const float4*)(Qf + go + 12);
        }
        f16x8 bfh[4], bfl[4], bfs[4];
#pragma unroll
        for (int j = 0; j < 4; j++) {
            size_t go = ((size_t)(ntb + j) * (DM / 32) + kk) * 512 + (size_t)lane * 8;
            bfh[j] = *(const f16x8*)(EHs + go);
            bfl[j] = *(const f16x8*)(ELs + go);
        }
        __syncthreads();
        f16x8 af[2][4], afs[4];
#pragma unroll
        for (int i = 0; i < 4; i++) {
            int ro = (wm + i * 16 + (lane & 15)) * 32 + quad;
            af[0][i] = *(const f16x8*)&sA[buf][0][ro];
            af[1][i] = *(const f16x8*)&sA[buf][1][ro];
            afs[i] = scl6(af[0][i]);
        }
#pragma unroll
        for (int j = 0; j < 4; j++) bfs[j] = scl6(bfh[j]);
#pragma unroll
        for (int i = 0; i < 4; i++)
#pragma unroll
            for (int j = 0; j < 4; j++) {
                acc[i][j] = __builtin_amdgcn_mfma_f32_16x16x32_f16(af[0][i], bfh[j], acc[i][j], 0, 0, 0);
                acc[i][j] = __builtin_amdgcn_mfma_f32_16x16x32_f16(afs[i],   bfl[j], acc[i][j], 0, 0, 0);
                acc[i][j] = __builtin_amdgcn_mfma_f32_16x16x32_f16(af[1][i], bfs[j], acc[i][j], 0, 0, 0);
            }
    }
    const int r0 = (lane >> 4) * 4, c0l = lane & 15;
#pragma unroll
    for (int i = 0; i < 4; i++)
#pragma unroll
        for (int v = 0; v < 4; v++) {
            int row = m0 + wm + i * 16 + r0 + v;
#pragma unroll
            for (int j = 0; j < 4; j++) {
                size_t idx = (size_t)row * CP + n0 + wn + j * 16 + c0l;
                float a = (float)AH[idx] * 0.015625f;
                float po = Pst[idx];
                Pst[idx] = a + fmaxf(po - THRC, 0.f) - acc[i][j][v];
            }
        }
}

// FAST kg2: A from swizzled Q pair; no LDS/barrier. Epilogue writes P fp32 AND
// s_new = 2*relu(P_new-thr) - P_new as swizzled fp16 pair (kg1's A input).
__global__ __launch_bounds__(256) void kg2f(const _Float16* __restrict__ QH,
                                            const _Float16* __restrict__ QL,
                                            const _Float16* __restrict__ EHs,
                                            const _Float16* __restrict__ ELs,
                                            const _Float16* __restrict__ AH,
                                            float* __restrict__ Pst,
                                            _Float16* __restrict__ SH,
                                            _Float16* __restrict__ SL) {
    const int id = blockIdx.x;
    const int nb = id % 80;
    const int mb = id / 80;
    if (nb >= 79) return;
    const int n0 = nb * 128;
    const int m0 = mb * 128;
    const int tid = threadIdx.x;
    const int lane = tid & 63;
    const int wvu = tid >> 6;
    const int wm = (wvu >> 1) * 64, wn = (wvu & 1) * 64;
    f32x4 acc[4][4] = {};

    const int mtb = (m0 + wm) >> 4;
    const int ntb = (n0 + wn) >> 4;

    for (int kk = 0; kk < DM / 32; ++kk) {
        f16x8 ah[4], al[4], bh[4], bl[4];
#pragma unroll
        for (int i = 0; i < 4; i++) {
            size_t go = ((size_t)(mtb + i) * (DM / 32) + kk) * 512 + (size_t)lane * 8;
            ah[i] = *(const f16x8*)(QH + go);
            al[i] = *(const f16x8*)(QL + go);
        }
#pragma unroll
        for (int j = 0; j < 4; j++) {
            size_t go = ((size_t)(ntb + j) * (DM / 32) + kk) * 512 + (size_t)lane * 8;
            bh[j] = *(const f16x8*)(EHs + go);
            bl[j] = *(const f16x8*)(ELs + go);
        }
        f16x8 as_[4], bs_[4];
#pragma unroll
        for (int i = 0; i < 4; i++) as_[i] = scl6(ah[i]);
#pragma unroll
        for (int j = 0; j < 4; j++) bs_[j] = scl6(bh[j]);
#pragma unroll
        for (int i = 0; i < 4; i++)
#pragma unroll
            for (int j = 0; j < 4; j++) {
                acc[i][j] = __builtin_amdgcn_mfma_f32_16x16x32_f16(ah[i],  bh[j],  acc[i][j], 0, 0, 0);
                acc[i][j] = __builtin_amdgcn_mfma_f32_16x16x32_f16(as_[i], bl[j],  acc[i][j], 0, 0, 0);
                acc[i][j] = __builtin_amdgcn_mfma_f32_16x16x32_f16(al[i],  bs_[j], acc[i][j], 0, 0, 0);
            }
    }
    const int r0 = (lane >> 4) * 4, c0l = lane & 15;
#pragma unroll
    for (int i = 0; i < 4; i++)
#pragma unroll
        for (int v = 0; v < 4; v++) {
            int row = m0 + wm + i * 16 + r0 + v;
#pragma unroll
            for (int j = 0; j < 4; j++) {
                int col = n0 + wn + j * 16 + c0l;
                size_t idx = (size_t)row * CP + col;
                float a = (float)AH[idx] * 0.015625f;
                float po = Pst[idx];
                float Pn = a + fmaxf(po - THRC, 0.f) - acc[i][j][v];
                Pst[idx] = Pn;
                float zn = fmaxf(Pn - THRC, 0.f);
                float s = 2.f * zn - Pn;
                _Float16 h = (_Float16)s;
                _Float16 l = (_Float16)((s - (float)h) * 64.f);
                size_t so = ((size_t)(row >> 4) * (CP / 32) + (col >> 5)) * 512
                          + (size_t)((((col >> 3) & 3) * 16 + (row & 15)) * 8 + (col & 7));
                SH[so] = h;
                SL[so] = l;
            }
        }
}

// final: recon = normalize(normalize(Qf) + mean)
__global__ __launch_bounds__(256) void kfinal(const float* __restrict__ Qf,
                                              const float* __restrict__ mean,
                                              float* __restrict__ out) {
    int row = blockIdx.x, t = threadIdx.x;
    int off = row * DM + t * 2;
    float2 q = *(const float2*)(Qf + off);
    float rx = q.x, ry = q.y;
    float ss = blk_sum256(rx * rx + ry * ry);
    float inv = 1.0f / fmaxf(sqrtf(ss), 1e-12f);
    rx *= inv; ry *= inv;
    float2 mm = *(const float2*)(mean + t * 2);
    rx += mm.x; ry += mm.y;
    float ss2 = blk_sum256(rx * rx + ry * ry);
    float inv2 = 1.0f / fmaxf(sqrtf(ss2), 1e-12f);
    float2 o = {rx * inv2, ry * inv2};
    *(float2*)(out + off) = o;
}

extern "C" void kernel_launch(void* const* d_in, const int* in_sizes, int n_in,
                              void* d_out, int out_size, void* d_ws, size_t ws_size,
                              hipStream_t stream) {
    const float* image = (const float*)d_in[0];
    const float* text  = (const float*)d_in[1];
    const float* mean  = (const float*)d_in[2];
    const float* D     = (const float*)d_in[3];
    float* out = (float*)d_out;
    float* ws = (float*)d_ws;

    // ---- workspace layout (float offsets) ----
    const size_t PL = (size_t)DM * CP / 2;     // [512][CP]-sized fp16 plane, in float units
    float* Y    = ws;                          // 524288 (loop: Qf)
    float* G    = ws + 524288;
    float* Xa   = G + 262144;
    float* Xb   = Xa + 262144;
    float* Tns  = Xb + 262144;
    _Float16* DHs = (_Float16*)(Tns + 262144);
    _Float16* DLs = (_Float16*)((float*)DHs + PL);
    _Float16* EHs = (_Float16*)((float*)DLs + PL);
    _Float16* ELs = (_Float16*)((float*)EHs + PL);
    _Float16* AH = (_Float16*)((float*)ELs + PL);      // a*64 fp16 [1024][CP]
    float* aD   = (float*)AH + (size_t)BDIM * CP / 2;  // fp32 [1024][512]
    float* P    = aD + (size_t)BDIM * DM;              // fp32 [1024][CP]
    float* gmax = P + (size_t)BDIM * CP;               // 64
    // fast-path extension:
    const size_t SPL = (size_t)BDIM * CP / 2;          // [1024][CP] fp16 plane, float units
    _Float16* SH = (_Float16*)(gmax + 64);
    _Float16* SL = (_Float16*)((float*)SH + SPL);
    _Float16* QHs = (_Float16*)((float*)SL + SPL);
    _Float16* QLs = (_Float16*)((float*)QHs + (size_t)BDIM * DM / 2);
    const size_t need_fast = ((size_t)((float*)QLs - ws) + (size_t)BDIM * DM / 2) * 4;
    const bool fast = ws_size >= need_fast;
    // setup-only aliases:
    float* Dt32 = P;
    float* Et32 = (float*)AH;
    // loop-time alias:
    float* Qf = Y;

    // --- setup ---
    knorm_rows<<<BDIM, 256, 0, stream>>>(text, out + (size_t)BDIM * DM);
    kprep_Y<<<BDIM, 256, 0, stream>>>(image, mean, Y);
    ktrs<<<dim3(CP / 64, DM / 64), 256, 0, stream>>>(D, Dt32, DHs, DLs, CREAL, DM, CP);
    kG<<<dim3(8, 8), 256, 0, stream>>>(Dt32, G);
    (void)hipMemsetAsync(gmax, 0, 4, stream);
    krow_abssum<<<DM, 64, 0, stream>>>(G, gmax);
    kinit_X0<<<DM * DM / 256, 256, 0, stream>>>(gmax, Xa);
    float* xc = Xa;
    float* xn = Xb;
    for (int it = 0; it < NSIT; ++it) {
        kgemm_ns_T<<<dim3(8, 8), 256, 0, stream>>>(G, xc, Tns);
        kgemm_ns_X<<<dim3(8, 8), 256, 0, stream>>>(xc, Tns, xn);
        float* tmp = xc; xc = xn; xn = tmp;
    }
    float* Ginv = xc;
    kgemm_nn64<0><<<dim3(CP / 64, DM / 64), 256, 0, stream>>>(Ginv, Dt32, Et32, nullptr);
    ktrs<<<dim3(DM / 64, CP / 64), 256, 0, stream>>>(Et32, nullptr, EHs, ELs, DM, CP, DM);
    kgemm_nn64<1><<<dim3(CP / 64, BDIM / 64), 256, 0, stream>>>(Y, Dt32, nullptr, AH);
    kgemm_aD<<<dim3(DM / 64, BDIM / 64), 256, 0, stream>>>(Y, G, aD);
    (void)hipMemsetAsync(P, 0, (size_t)BDIM * CP * sizeof(float), stream);
    if (fast) {
        // s(P=0) = 0 -> zero both planes
        (void)hipMemsetAsync(SH, 0, SPL * 4, stream);
        (void)hipMemsetAsync(SL, 0, SPL * 4, stream);
    }

    // --- ADMM main loop ---
    for (int it = 0; it < NIT; ++it) {
        (void)hipMemsetAsync(Qf, 0, (size_t)BDIM * DM * sizeof(float), stream);
        if (fast) {
            kg1s<<<512, 256, 0, stream>>>(SH, SL, DHs, DLs, aD, Qf);
            kredQ<<<BDIM * DM / 8 / 256, 256, 0, stream>>>(Qf, QHs, QLs);
            kg2f<<<640, 256, 0, stream>>>(QHs, QLs, EHs, ELs, AH, P, SH, SL);
        } else {
            kg1p<0><<<512, 256, 0, stream>>>(P, DHs, DLs, aD, Qf);
            kg2o<<<640, 256, 0, stream>>>(Qf, EHs, ELs, AH, P);
        }
    }

    // --- finalize: recon = normalize(normalize(z @ Dp) + mean) ---
    (void)hipMemsetAsync(Qf, 0, (size_t)BDIM * DM * sizeof(float), stream);
    kg1p<1><<<512, 256, 0, stream>>>(P, DHs, DLs, aD, Qf);
    kfinal<<<BDIM, 256, 0, stream>>>(Qf, mean, out);
}

// Round 12
// 11687.208 us; speedup vs baseline: 1.9618x; 1.9618x over previous
//
#include <hip/hip_runtime.h>
#include <cstddef>
#include <cstdint>

// Problem constants
#define BDIM  1024        // batch rows
#define DM    512         // embedding dim
#define CREAL 10000       // dictionary atoms
#define CP    10112       // padded atoms = 79*128 = 158*64 = 316*32
#define KSPL  16          // split-K chunks for GEMM1 (private partial buffers)
#define RHOC  5.0f
#define THRC  (0.01f/5.0f)
#define NIT   100
#define NSIT  12

typedef float f32x4 __attribute__((ext_vector_type(4)));
typedef _Float16 f16x8 __attribute__((ext_vector_type(8)));

// ---------------- helpers ----------------

// Split scheme: x ~ h + l/64, h = fp16(x), l = fp16((x-h)*64)  (pair error ~2^-24 rel).
// GEMM terms: h*h + (h*2^-6)*l_B + l_A*(h*2^-6)  — dropped l*l term ~2^-24 rel.
__device__ __forceinline__ f16x8 scl6(f16x8 v) {
    f16x8 r;
#pragma unroll
    for (int i = 0; i < 8; i++) r[i] = v[i] * (_Float16)0.015625f;  // exact exponent shift
    return r;
}

__device__ __forceinline__ float blk_sum256(float v) {
    __shared__ float sb[4];
#pragma unroll
    for (int o = 32; o; o >>= 1) v += __shfl_down(v, o, 64);
    int lane = threadIdx.x & 63, w = threadIdx.x >> 6;
    __syncthreads();
    if (lane == 0) sb[w] = v;
    __syncthreads();
    return sb[0] + sb[1] + sb[2] + sb[3];
}

// txt = normalize(text) per row
__global__ __launch_bounds__(256) void knorm_rows(const float* __restrict__ X,
                                                  float* __restrict__ out) {
    int row = blockIdx.x, t = threadIdx.x;
    int off = row * DM + t * 2;
    float2 v = *(const float2*)(X + off);
    float ss = blk_sum256(v.x * v.x + v.y * v.y);
    float inv = 1.0f / fmaxf(sqrtf(ss), 1e-12f);
    float2 o = {v.x * inv, v.y * inv};
    *(float2*)(out + off) = o;
}

// Y = normalize(normalize(image) - mean) per row
__global__ __launch_bounds__(256) void kprep_Y(const float* __restrict__ img,
                                               const float* __restrict__ mean,
                                               float* __restrict__ Y) {
    int row = blockIdx.x, t = threadIdx.x;
    int off = row * DM + t * 2;
    float2 v = *(const float2*)(img + off);
    float ss = blk_sum256(v.x * v.x + v.y * v.y);
    float inv = 1.0f / fmaxf(sqrtf(ss), 1e-12f);
    float2 mm = *(const float2*)(mean + t * 2);
    float tx = v.x * inv - mm.x, ty = v.y * inv - mm.y;
    float ss2 = blk_sum256(tx * tx + ty * ty);
    float inv2 = 1.0f / fmaxf(sqrtf(ss2), 1e-12f);
    float2 o = {tx * inv2, ty * inv2};
    *(float2*)(Y + off) = o;
}

// transpose (+zero-pad rows>=Rvalid), split to fp16 h/l pair (l stored *64) and write
// the fp16 planes in MFMA FRAGMENT-SWIZZLED order:
//   plane idx = (rowtile16 * (ncols/32) + coltile32)*512 + (kquad*16 + row&15)*8 + (col&7)
// so a wave's fragment load is base + lane*8 (fully coalesced, no LDS needed).
// optional fp32 out = reconstructed pair (h + l/64), ROW-MAJOR.
__global__ __launch_bounds__(256) void ktrs(const float* __restrict__ in,
                                            float* __restrict__ out32,
                                            _Float16* __restrict__ oH,
                                            _Float16* __restrict__ oL,
                                            int Rvalid, int Cin, int Rout) {
    __shared__ float tile[64][65];
    int r0 = blockIdx.x * 64;   // rows of in  (cols of out)
    int c0 = blockIdx.y * 64;   // cols of in  (rows of out)
    int t = threadIdx.x;
    int ri = r0 + (t >> 2);
    int cc = (t & 3) * 16;
#pragma unroll
    for (int q = 0; q < 4; ++q) {
        float4 v = {0.f, 0.f, 0.f, 0.f};
        if (ri < Rvalid) v = *(const float4*)(in + (size_t)ri * Cin + c0 + cc + q * 4);
        *(float4*)&tile[t >> 2][cc + q * 4] = v;
    }
    __syncthreads();
    int oc = c0 + (t >> 2);            // out row
    int orr = r0 + (t & 3) * 16;       // out col base (multiple of 16)
    _Float16 hv[16], lv[16];
#pragma unroll
    for (int q = 0; q < 16; ++q) {
        float v = tile[(t & 3) * 16 + q][t >> 2];
        _Float16 h = (_Float16)v;
        _Float16 l = (_Float16)((v - (float)h) * 64.f);
        hv[q] = h; lv[q] = l;
        if (out32) out32[(size_t)oc * Rout + orr + q] = (float)h + (float)l * 0.015625f;
    }
    int rt = oc >> 4, rin = oc & 15;
    int kt = orr >> 5;
    int kq0 = (orr >> 3) & 3;          // 0 or 2
    size_t base = ((size_t)rt * (Rout >> 5) + kt) * 512;
    *(f16x8*)(oH + base + (size_t)(kq0 * 16 + rin) * 8)       = *(f16x8*)&hv[0];
    *(f16x8*)(oH + base + (size_t)((kq0 + 1) * 16 + rin) * 8) = *(f16x8*)&hv[8];
    *(f16x8*)(oL + base + (size_t)(kq0 * 16 + rin) * 8)       = *(f16x8*)&lv[0];
    *(f16x8*)(oL + base + (size_t)((kq0 + 1) * 16 + rin) * 8) = *(f16x8*)&lv[8];
}

// G = Dt*Dt^T + rho I  (Dt [512][CP] fp32; 64x64 tiles, K=CP)
__global__ __launch_bounds__(256) void kG(const float* __restrict__ Dt,
                                          float* __restrict__ G) {
    __shared__ float As[32][68];
    __shared__ float Bs[32][68];
    int tid = threadIdx.x;
    int j0 = blockIdx.x * 64, i0 = blockIdx.y * 64;
    int tn = (tid & 15) * 4, tm = (tid >> 4) * 4;
    float acc[4][4];
#pragma unroll
    for (int i = 0; i < 4; i++)
#pragma unroll
        for (int j = 0; j < 4; j++) acc[i][j] = 0.f;
    for (int k0 = 0; k0 < CP; k0 += 32) {
        __syncthreads();
#pragma unroll
        for (int p = 0; p < 2; ++p) {
            int idx = tid + p * 256;
            int row = idx >> 3, kv = (idx & 7) << 2;
            float4 va = *(const float4*)(Dt + (size_t)(i0 + row) * CP + k0 + kv);
            As[kv + 0][row] = va.x; As[kv + 1][row] = va.y;
            As[kv + 2][row] = va.z; As[kv + 3][row] = va.w;
            float4 vb = *(const float4*)(Dt + (size_t)(j0 + row) * CP + k0 + kv);
            Bs[kv + 0][row] = vb.x; Bs[kv + 1][row] = vb.y;
            Bs[kv + 2][row] = vb.z; Bs[kv + 3][row] = vb.w;
        }
        __syncthreads();
#pragma unroll
        for (int k = 0; k < 32; ++k) {
            float4 a4 = *(const float4*)&As[k][tm];
            float4 b4 = *(const float4*)&Bs[k][tn];
            float af[4] = {a4.x, a4.y, a4.z, a4.w};
            float bf[4] = {b4.x, b4.y, b4.z, b4.w};
#pragma unroll
            for (int i = 0; i < 4; i++)
#pragma unroll
                for (int j = 0; j < 4; j++) acc[i][j] = fmaf(af[i], bf[j], acc[i][j]);
        }
    }
#pragma unroll
    for (int i = 0; i < 4; i++)
#pragma unroll
        for (int j = 0; j < 4; j++) {
            int gi = i0 + tm + i, gj = j0 + tn + j;
            G[gi * DM + gj] = acc[i][j] + ((gi == gj) ? RHOC : 0.f);
        }
}

__global__ void krow_abssum(const float* __restrict__ G, float* __restrict__ gmax) {
    int row = blockIdx.x, t = threadIdx.x;   // 64 threads = 1 wave
    float s = 0.f;
    for (int j = t; j < DM; j += 64) s += fabsf(G[row * DM + j]);
#pragma unroll
    for (int o = 32; o; o >>= 1) s += __shfl_down(s, o, 64);
    if (t == 0) atomicMax((int*)gmax, __float_as_int(s));
}

__global__ void kinit_X0(const float* __restrict__ gmax, float* __restrict__ X) {
    int idx = blockIdx.x * 256 + threadIdx.x;
    int i = idx >> 9, j = idx & 511;
    X[idx] = (i == j) ? (1.0f / gmax[0]) : 0.0f;
}

// T = G @ X (512^3 NN, 64x64 tiles)
__global__ __launch_bounds__(256) void kgemm_ns_T(const float* __restrict__ G,
                                                  const float* __restrict__ X,
                                                  float* __restrict__ T) {
    __shared__ float As[32][68];
    __shared__ float Bs[32][68];
    int tid = threadIdx.x;
    int n0 = blockIdx.x * 64, m0 = blockIdx.y * 64;
    int tn = (tid & 15) * 4, tm = (tid >> 4) * 4;
    float acc[4][4];
#pragma unroll
    for (int i = 0; i < 4; i++)
#pragma unroll
        for (int j = 0; j < 4; j++) acc[i][j] = 0.f;
    for (int k0 = 0; k0 < DM; k0 += 32) {
        __syncthreads();
#pragma unroll
        for (int p = 0; p < 2; ++p) {
            int idx = tid + p * 256;
            {
                int row = idx >> 3, kv = (idx & 7) << 2;
                float4 v = *(const float4*)(G + (m0 + row) * DM + k0 + kv);
                As[kv + 0][row] = v.x; As[kv + 1][row] = v.y;
                As[kv + 2][row] = v.z; As[kv + 3][row] = v.w;
            }
            {
                int r = idx >> 4, cv = (idx & 15) << 2;
                *(float4*)&Bs[r][cv] = *(const float4*)(X + (k0 + r) * DM + n0 + cv);
            }
        }
        __syncthreads();
#pragma unroll
        for (int k = 0; k < 32; ++k) {
            float4 a4 = *(const float4*)&As[k][tm];
            float4 b4 = *(const float4*)&Bs[k][tn];
            float af[4] = {a4.x, a4.y, a4.z, a4.w};
            float bf[4] = {b4.x, b4.y, b4.z, b4.w};
#pragma unroll
            for (int i = 0; i < 4; i++)
#pragma unroll
                for (int j = 0; j < 4; j++) acc[i][j] = fmaf(af[i], bf[j], acc[i][j]);
        }
    }
#pragma unroll
    for (int i = 0; i < 4; i++) {
        float4 o = {acc[i][0], acc[i][1], acc[i][2], acc[i][3]};
        *(float4*)(T + (m0 + tm + i) * DM + n0 + tn) = o;
    }
}

// Xn = 2*Xo - Xo @ T
__global__ __launch_bounds__(256) void kgemm_ns_X(const float* __restrict__ Xo,
                                                  const float* __restrict__ T,
                                                  float* __restrict__ Xn) {
    __shared__ float As[32][68];
    __shared__ float Bs[32][68];
    int tid = threadIdx.x;
    int n0 = blockIdx.x * 64, m0 = blockIdx.y * 64;
    int tn = (tid & 15) * 4, tm = (tid >> 4) * 4;
    float acc[4][4];
#pragma unroll
    for (int i = 0; i < 4; i++)
#pragma unroll
        for (int j = 0; j < 4; j++) acc[i][j] = 0.f;
    for (int k0 = 0; k0 < DM; k0 += 32) {
        __syncthreads();
#pragma unroll
        for (int p = 0; p < 2; ++p) {
            int idx = tid + p * 256;
            {
                int row = idx >> 3, kv = (idx & 7) << 2;
                float4 v = *(const float4*)(Xo + (m0 + row) * DM + k0 + kv);
                As[kv + 0][row] = v.x; As[kv + 1][row] = v.y;
                As[kv + 2][row] = v.z; As[kv + 3][row] = v.w;
            }
            {
                int r = idx >> 4, cv = (idx & 15) << 2;
                *(float4*)&Bs[r][cv] = *(const float4*)(T + (k0 + r) * DM + n0 + cv);
            }
        }
        __syncthreads();
#pragma unroll
        for (int k = 0; k < 32; ++k) {
            float4 a4 = *(const float4*)&As[k][tm];
            float4 b4 = *(const float4*)&Bs[k][tn];
            float af[4] = {a4.x, a4.y, a4.z, a4.w};
            float bf[4] = {b4.x, b4.y, b4.z, b4.w};
#pragma unroll
            for (int i = 0; i < 4; i++)
#pragma unroll
                for (int j = 0; j < 4; j++) acc[i][j] = fmaf(af[i], bf[j], acc[i][j]);
        }
    }
#pragma unroll
    for (int i = 0; i < 4; i++) {
        int base = (m0 + tm + i) * DM + n0 + tn;
        float4 xo = *(const float4*)(Xo + base);
        float4 o = {2.f * xo.x - acc[i][0], 2.f * xo.y - acc[i][1],
                    2.f * xo.z - acc[i][2], 2.f * xo.w - acc[i][3]};
        *(float4*)(Xn + base) = o;
    }
}

// NN fp32: out[M][CP] = A[M][512] @ B[512][CP]
// MODE 0: store fp32. MODE 1: store a = acc*0.2 as fp16 scaled by 64.
template <int MODE>
__global__ __launch_bounds__(256) void kgemm_nn64(const float* __restrict__ A,
                                                  const float* __restrict__ B,
                                                  float* __restrict__ out32,
                                                  _Float16* __restrict__ oA) {
    __shared__ float As[32][68];
    __shared__ float Bs[32][68];
    int tid = threadIdx.x;
    int n0 = blockIdx.x * 64, m0 = blockIdx.y * 64;
    int tn = (tid & 15) * 4, tm = (tid >> 4) * 4;
    float acc[4][4];
#pragma unroll
    for (int i = 0; i < 4; i++)
#pragma unroll
        for (int j = 0; j < 4; j++) acc[i][j] = 0.f;
    for (int k0 = 0; k0 < DM; k0 += 32) {
        __syncthreads();
#pragma unroll
        for (int p = 0; p < 2; ++p) {
            int idx = tid + p * 256;
            {
                int row = idx >> 3, kv = (idx & 7) << 2;
                float4 v = *(const float4*)(A + (size_t)(m0 + row) * DM + k0 + kv);
                As[kv + 0][row] = v.x; As[kv + 1][row] = v.y;
                As[kv + 2][row] = v.z; As[kv + 3][row] = v.w;
            }
            {
                int r = idx >> 4, cv = (idx & 15) << 2;
                *(float4*)&Bs[r][cv] = *(const float4*)(B + (size_t)(k0 + r) * CP + n0 + cv);
            }
        }
        __syncthreads();
#pragma unroll
        for (int k = 0; k < 32; ++k) {
            float4 a4 = *(const float4*)&As[k][tm];
            float4 b4 = *(const float4*)&Bs[k][tn];
            float af[4] = {a4.x, a4.y, a4.z, a4.w};
            float bf[4] = {b4.x, b4.y, b4.z, b4.w};
#pragma unroll
            for (int i = 0; i < 4; i++)
#pragma unroll
                for (int j = 0; j < 4; j++) acc[i][j] = fmaf(af[i], bf[j], acc[i][j]);
        }
    }
#pragma unroll
    for (int i = 0; i < 4; i++)
#pragma unroll
        for (int j = 0; j < 4; j++) {
            size_t idx = (size_t)(m0 + tm + i) * CP + n0 + tn + j;
            if (MODE == 0) out32[idx] = acc[i][j];
            else           oA[idx] = (_Float16)(acc[i][j] * 0.2f * 64.f);
        }
}

// aD = Y@G/rho - Y   (out [1024][512]; 64x64 tiles, K=512)
__global__ __launch_bounds__(256) void kgemm_aD(const float* __restrict__ Yb,
                                                const float* __restrict__ G,
                                                float* __restrict__ aD) {
    __shared__ float As[32][68];
    __shared__ float Bs[32][68];
    int tid = threadIdx.x;
    int n0 = blockIdx.x * 64, m0 = blockIdx.y * 64;
    int tn = (tid & 15) * 4, tm = (tid >> 4) * 4;
    float acc[4][4];
#pragma unroll
    for (int i = 0; i < 4; i++)
#pragma unroll
        for (int j = 0; j < 4; j++) acc[i][j] = 0.f;
    for (int k0 = 0; k0 < DM; k0 += 32) {
        __syncthreads();
#pragma unroll
        for (int p = 0; p < 2; ++p) {
            int idx = tid + p * 256;
            {
                int row = idx >> 3, kv = (idx & 7) << 2;
                float4 v = *(const float4*)(Yb + (size_t)(m0 + row) * DM + k0 + kv);
                As[kv + 0][row] = v.x; As[kv + 1][row] = v.y;
                As[kv + 2][row] = v.z; As[kv + 3][row] = v.w;
            }
            {
                int r = idx >> 4, cv = (idx & 15) << 2;
                *(float4*)&Bs[r][cv] = *(const float4*)(G + (k0 + r) * DM + n0 + cv);
            }
        }
        __syncthreads();
#pragma unroll
        for (int k = 0; k < 32; ++k) {
            float4 a4 = *(const float4*)&As[k][tm];
            float4 b4 = *(const float4*)&Bs[k][tn];
            float af[4] = {a4.x, a4.y, a4.z, a4.w};
            float bf[4] = {b4.x, b4.y, b4.z, b4.w};
#pragma unroll
            for (int i = 0; i < 4; i++)
#pragma unroll
                for (int j = 0; j < 4; j++) acc[i][j] = fmaf(af[i], bf[j], acc[i][j]);
        }
    }
#pragma unroll
    for (int i = 0; i < 4; i++) {
        int base = (m0 + tm + i) * DM + n0 + tn;
        float4 y4 = *(const float4*)(Yb + base);
        float4 o = {acc[i][0] * 0.2f - y4.x, acc[i][1] * 0.2f - y4.y,
                    acc[i][2] * 0.2f - y4.z, acc[i][3] * 0.2f - y4.w};
        *(float4*)(aD + base) = o;
    }
}

// ---------------- MFMA fp16-pair GEMMs (swizzled-B, partial-buffer split-K) ----------------
// A-frag: A[m=lane&15][k=(lane>>4)*8+j]; B-frag mirrored; C/D: col=lane&15, row=(lane>>4)*4+reg.
// B planes FRAGMENT-SWIZZLED in global (base+lane*8, 1KB/wave coalesced). A via
// double-buffered LDS, single barrier/k-step, register-prefetched P.
// Split-K via PRIVATE per-ks partial buffers (plain stores) + deterministic kred
// reduction — no device-scope atomics (round-12 change).

// GEMM1 partial: Qp[ks] = (z-u) @ Dp over this ks's K-chunk of CP.
// grid: 1-D, 512 blocks; id = mb*64 + (ks*4 + nb)
// MODE 0: v = (P>thr)? P-2thr : -P ;  MODE 1: v = relu(P-thr)  (final z@Dp)
template <int MODE>
__global__ __launch_bounds__(256) void kg1(const float* __restrict__ Pst,
                                           const _Float16* __restrict__ DHs,
                                           const _Float16* __restrict__ DLs,
                                           float* __restrict__ Qp) {
    __shared__ _Float16 sA[2][2][128 * 32];   // [buf][plane]
    const int id = blockIdx.x;
    const int g  = id & 63;            // (nb, ks) group
    const int mb = id >> 6;            // 0..7
    const int nb = g & 3;
    const int ks = g >> 2;
    const int n0 = nb * 128;           // over DM
    const int m0 = mb * 128;           // over BDIM
    const int tid = threadIdx.x;
    const int lane = tid & 63;
    const int wvu = tid >> 6;
    const int wm = (wvu >> 1) * 64, wn = (wvu & 1) * 64;
    const int arow = tid >> 1;         // 0..127
    const int aq = (tid & 1) * 16;     // 0 or 16
    const int quad = (lane >> 4) * 8;
    f32x4 acc[4][4] = {};

    const int steps = CP / 32;                    // 316
    const int per = (steps + KSPL - 1) / KSPL;    // 20
    int s0 = ks * per;
    int s1 = s0 + per; if (s1 > steps) s1 = steps;

    // preload P for first step
    float pv[16];
    {
        size_t go = (size_t)(m0 + arow) * CP + s0 * 32 + aq;
        *(float4*)&pv[0]  = *(const float4*)(Pst + go);
        *(float4*)&pv[4]  = *(const float4*)(Pst + go + 4);
        *(float4*)&pv[8]  = *(const float4*)(Pst + go + 8);
        *(float4*)&pv[12] = *(const float4*)(Pst + go + 12);
    }
    const int ntb = (n0 + wn) >> 4;    // B fragment row-tile base (over DM/16 tiles)

    for (int sp = s0; sp < s1; ++sp) {
        const int buf = (sp - s0) & 1;
        {   // split current pv -> LDS A (double-buffered)
            _Float16 th[16], tl[16];
#pragma unroll
            for (int e = 0; e < 16; ++e) {
                float p = pv[e];
                float v = (MODE == 0) ? ((p > THRC) ? p - 2.f * THRC : -p)
                                      : fmaxf(p - THRC, 0.f);
                _Float16 h = (_Float16)v;
                th[e] = h;
                tl[e] = (_Float16)((v - (float)h) * 64.f);
            }
            int lb = arow * 32 + aq;
            *(f16x8*)&sA[buf][0][lb]     = *(f16x8*)&th[0];
            *(f16x8*)&sA[buf][0][lb + 8] = *(f16x8*)&th[8];
            *(f16x8*)&sA[buf][1][lb]     = *(f16x8*)&tl[0];
            *(f16x8*)&sA[buf][1][lb + 8] = *(f16x8*)&tl[8];
        }
        // prefetch next step's P (latency hidden behind this step's MFMA)
        if (sp + 1 < s1) {
            size_t go = (size_t)(m0 + arow) * CP + (sp + 1) * 32 + aq;
            *(float4*)&pv[0]  = *(const float4*)(Pst + go);
            *(float4*)&pv[4]  = *(const float4*)(Pst + go + 4);
            *(float4*)&pv[8]  = *(const float4*)(Pst + go + 8);
            *(float4*)&pv[12] = *(const float4*)(Pst + go + 12);
        }
        // coalesced swizzled B fragments (1 KB/wave per load)
        f16x8 bfh[4], bfl[4], bfs[4];
#pragma unroll
        for (int j = 0; j < 4; j++) {
            size_t go = ((size_t)(ntb + j) * (CP / 32) + sp) * 512 + (size_t)lane * 8;
            bfh[j] = *(const f16x8*)(DHs + go);
            bfl[j] = *(const f16x8*)(DLs + go);
        }
        __syncthreads();   // single barrier: A writes visible
        f16x8 af[2][4], afs[4];
#pragma unroll
        for (int i = 0; i < 4; i++) {
            int ro = (wm + i * 16 + (lane & 15)) * 32 + quad;
            af[0][i] = *(const f16x8*)&sA[buf][0][ro];
            af[1][i] = *(const f16x8*)&sA[buf][1][ro];
            afs[i] = scl6(af[0][i]);
        }
#pragma unroll
        for (int j = 0; j < 4; j++) bfs[j] = scl6(bfh[j]);
#pragma unroll
        for (int i = 0; i < 4; i++)
#pragma unroll
            for (int j = 0; j < 4; j++) {
                acc[i][j] = __builtin_amdgcn_mfma_f32_16x16x32_f16(af[0][i], bfh[j], acc[i][j], 0, 0, 0);
                acc[i][j] = __builtin_amdgcn_mfma_f32_16x16x32_f16(afs[i],   bfl[j], acc[i][j], 0, 0, 0);
                acc[i][j] = __builtin_amdgcn_mfma_f32_16x16x32_f16(af[1][i], bfs[j], acc[i][j], 0, 0, 0);
            }
    }
    float* outp = Qp + (size_t)ks * (BDIM * DM);
    const int r0 = (lane >> 4) * 4, c0l = lane & 15;
#pragma unroll
    for (int i = 0; i < 4; i++)
#pragma unroll
        for (int v = 0; v < 4; v++) {
            int row = m0 + wm + i * 16 + r0 + v;
#pragma unroll
            for (int j = 0; j < 4; j++)
                outp[(size_t)row * DM + n0 + wn + j * 16 + c0l] = acc[i][j][v];
        }
}

// Qf = (addA ? aD : 0) + sum_ks Qp[ks]   (deterministic reduction)
__global__ void kred(const float* __restrict__ Qp, const float* __restrict__ aD,
                     float* __restrict__ Qf, int addA) {
    size_t b = ((size_t)blockIdx.x * 256 + threadIdx.x) * 4;
    float4 s = {0.f, 0.f, 0.f, 0.f};
    if (addA) s = *(const float4*)(aD + b);
#pragma unroll
    for (int q = 0; q < KSPL; q++) {
        float4 t = *(const float4*)(Qp + (size_t)q * (BDIM * DM) + b);
        s.x += t.x; s.y += t.y; s.z += t.z; s.w += t.w;
    }
    *(float4*)(Qf + b) = s;
}

// GEMM2: acc = Q @ E^T (out [1024][CP], K=512), fused ADMM epilogue (fp32 state):
//   P_new = a + relu(P_old - thr) - acc.  A built in-kernel from fp32 Qf (pair split).
// grid: 1-D, 640 blocks; id = mb*80 + nb (nb<79)
__global__ __launch_bounds__(256) void kg2(const float* __restrict__ Qf,
                                           const _Float16* __restrict__ EHs,
                                           const _Float16* __restrict__ ELs,
                                           const _Float16* __restrict__ AH,
                                           float* __restrict__ Pst) {
    __shared__ _Float16 sA[2][2][128 * 32];
    const int id = blockIdx.x;
    const int nb = id % 80;
    const int mb = id / 80;
    if (nb >= 79) return;
    const int n0 = nb * 128;           // over CP
    const int m0 = mb * 128;           // over BDIM
    const int tid = threadIdx.x;
    const int lane = tid & 63;
    const int wvu = tid >> 6;
    const int wm = (wvu >> 1) * 64, wn = (wvu & 1) * 64;
    const int arow = tid >> 1;
    const int aq = (tid & 1) * 16;
    const int quad = (lane >> 4) * 8;
    f32x4 acc[4][4] = {};

    float qv[16];
    {
        size_t go = (size_t)(m0 + arow) * DM + aq;
        *(float4*)&qv[0]  = *(const float4*)(Qf + go);
        *(float4*)&qv[4]  = *(const float4*)(Qf + go + 4);
        *(float4*)&qv[8]  = *(const float4*)(Qf + go + 8);
        *(float4*)&qv[12] = *(const float4*)(Qf + go + 12);
    }
    const int ntb = (n0 + wn) >> 4;    // B fragment row-tile base (over CP/16 tiles)

    for (int kk = 0; kk < DM / 32; ++kk) {
        const int buf = kk & 1;
        {   // split current qv -> LDS A
            _Float16 th[16], tl[16];
#pragma unroll
            for (int e = 0; e < 16; ++e) {
                float v = qv[e];
                _Float16 h = (_Float16)v;
                th[e] = h;
                tl[e] = (_Float16)((v - (float)h) * 64.f);
            }
            int lb = arow * 32 + aq;
            *(f16x8*)&sA[buf][0][lb]     = *(f16x8*)&th[0];
            *(f16x8*)&sA[buf][0][lb + 8] = *(f16x8*)&th[8];
            *(f16x8*)&sA[buf][1][lb]     = *(f16x8*)&tl[0];
            *(f16x8*)&sA[buf][1][lb + 8] = *(f16x8*)&tl[8];
        }
        // prefetch next step's Q
        if (kk + 1 < DM / 32) {
            size_t go = (size_t)(m0 + arow) * DM + (kk + 1) * 32 + aq;
            *(float4*)&qv[0]  = *(const float4*)(Qf + go);
            *(float4*)&qv[4]  = *(const float4*)(Qf + go + 4);
            *(float4*)&qv[8]  = *(const float4*)(Qf + go + 8);
            *(float4*)&qv[12] = *(const float4*)(Qf + go + 12);
        }
        // coalesced swizzled B fragments (E pair)
        f16x8 bfh[4], bfl[4], bfs[4];
#pragma unroll
        for (int j = 0; j < 4; j++) {
            size_t go = ((size_t)(ntb + j) * (DM / 32) + kk) * 512 + (size_t)lane * 8;
            bfh[j] = *(const f16x8*)(EHs + go);
            bfl[j] = *(const f16x8*)(ELs + go);
        }
        __syncthreads();
        f16x8 af[2][4], afs[4];
#pragma unroll
        for (int i = 0; i < 4; i++) {
            int ro = (wm + i * 16 + (lane & 15)) * 32 + quad;
            af[0][i] = *(const f16x8*)&sA[buf][0][ro];
            af[1][i] = *(const f16x8*)&sA[buf][1][ro];
            afs[i] = scl6(af[0][i]);
        }
#pragma unroll
        for (int j = 0; j < 4; j++) bfs[j] = scl6(bfh[j]);
#pragma unroll
        for (int i = 0; i < 4; i++)
#pragma unroll
            for (int j = 0; j < 4; j++) {
                acc[i][j] = __builtin_amdgcn_mfma_f32_16x16x32_f16(af[0][i], bfh[j], acc[i][j], 0, 0, 0);
                acc[i][j] = __builtin_amdgcn_mfma_f32_16x16x32_f16(afs[i],   bfl[j], acc[i][j], 0, 0, 0);
                acc[i][j] = __builtin_amdgcn_mfma_f32_16x16x32_f16(af[1][i], bfs[j], acc[i][j], 0, 0, 0);
            }
    }
    const int r0 = (lane >> 4) * 4, c0l = lane & 15;
#pragma unroll
    for (int i = 0; i < 4; i++)
#pragma unroll
        for (int v = 0; v < 4; v++) {
            int row = m0 + wm + i * 16 + r0 + v;
#pragma unroll
            for (int j = 0; j < 4; j++) {
                size_t idx = (size_t)row * CP + n0 + wn + j * 16 + c0l;
                float a = (float)AH[idx] * 0.015625f;
                float po = Pst[idx];
                Pst[idx] = a + fmaxf(po - THRC, 0.f) - acc[i][j][v];
            }
        }
}

// final: recon = normalize(normalize(Qf) + mean)
__global__ __launch_bounds__(256) void kfinal(const float* __restrict__ Qf,
                                              const float* __restrict__ mean,
                                              float* __restrict__ out) {
    int row = blockIdx.x, t = threadIdx.x;
    int off = row * DM + t * 2;
    float2 q = *(const float2*)(Qf + off);
    float rx = q.x, ry = q.y;
    float ss = blk_sum256(rx * rx + ry * ry);
    float inv = 1.0f / fmaxf(sqrtf(ss), 1e-12f);
    rx *= inv; ry *= inv;
    float2 mm = *(const float2*)(mean + t * 2);
    rx += mm.x; ry += mm.y;
    float ss2 = blk_sum256(rx * rx + ry * ry);
    float inv2 = 1.0f / fmaxf(sqrtf(ss2), 1e-12f);
    float2 o = {rx * inv2, ry * inv2};
    *(float2*)(out + off) = o;
}

extern "C" void kernel_launch(void* const* d_in, const int* in_sizes, int n_in,
                              void* d_out, int out_size, void* d_ws, size_t ws_size,
                              hipStream_t stream) {
    const float* image = (const float*)d_in[0];
    const float* text  = (const float*)d_in[1];
    const float* mean  = (const float*)d_in[2];
    const float* D     = (const float*)d_in[3];
    float* out = (float*)d_out;
    float* ws = (float*)d_ws;

    // ---- workspace layout (float offsets); total ~36.4M floats = 145.8 MB ----
    // (round 11's 155.5 MB fast path executed -> ws_size >= 155 MB, so this fits)
    const size_t PL = (size_t)DM * CP / 2;     // [512][CP]-sized fp16 plane, in float units
    float* Y    = ws;                          // 524288 (loop: Qf)
    float* G    = ws + 524288;
    float* Xa   = G + 262144;
    float* Xb   = Xa + 262144;
    float* Tns  = Xb + 262144;
    _Float16* DHs = (_Float16*)(Tns + 262144); // 4 fp16 planes (fragment-swizzled)
    _Float16* DLs = (_Float16*)((float*)DHs + PL);
    _Float16* EHs = (_Float16*)((float*)DLs + PL);
    _Float16* ELs = (_Float16*)((float*)EHs + PL);
    _Float16* AH = (_Float16*)((float*)ELs + PL);      // a*64 fp16 [1024][CP]
    float* aD   = (float*)AH + (size_t)BDIM * CP / 2;  // fp32 [1024][512]
    float* P    = aD + (size_t)BDIM * DM;              // fp32 [1024][CP]
    float* gmax = P + (size_t)BDIM * CP;               // 64
    float* Qp   = gmax + 64;                           // KSPL x [1024][512] partials
    // setup-only aliases:
    float* Dt32 = P;
    float* Et32 = (float*)AH;
    // loop-time alias:
    float* Qf = Y;

    // --- setup ---
    knorm_rows<<<BDIM, 256, 0, stream>>>(text, out + (size_t)BDIM * DM);
    kprep_Y<<<BDIM, 256, 0, stream>>>(image, mean, Y);
    ktrs<<<dim3(CP / 64, DM / 64), 256, 0, stream>>>(D, Dt32, DHs, DLs, CREAL, DM, CP);
    kG<<<dim3(8, 8), 256, 0, stream>>>(Dt32, G);
    (void)hipMemsetAsync(gmax, 0, 4, stream);
    krow_abssum<<<DM, 64, 0, stream>>>(G, gmax);
    kinit_X0<<<DM * DM / 256, 256, 0, stream>>>(gmax, Xa);
    float* xc = Xa;
    float* xn = Xb;
    for (int it = 0; it < NSIT; ++it) {
        kgemm_ns_T<<<dim3(8, 8), 256, 0, stream>>>(G, xc, Tns);
        kgemm_ns_X<<<dim3(8, 8), 256, 0, stream>>>(xc, Tns, xn);
        float* tmp = xc; xc = xn; xn = tmp;
    }
    float* Ginv = xc;
    kgemm_nn64<0><<<dim3(CP / 64, DM / 64), 256, 0, stream>>>(Ginv, Dt32, Et32, nullptr);
    ktrs<<<dim3(DM / 64, CP / 64), 256, 0, stream>>>(Et32, nullptr, EHs, ELs, DM, CP, DM);
    kgemm_nn64<1><<<dim3(CP / 64, BDIM / 64), 256, 0, stream>>>(Y, Dt32, nullptr, AH);
    kgemm_aD<<<dim3(DM / 64, BDIM / 64), 256, 0, stream>>>(Y, G, aD);
    (void)hipMemsetAsync(P, 0, (size_t)BDIM * CP * sizeof(float), stream);

    // --- ADMM main loop (no atomics, no per-iter memset) ---
    for (int it = 0; it < NIT; ++it) {
        kg1<0><<<512, 256, 0, stream>>>(P, DHs, DLs, Qp);
        kred<<<BDIM * DM / 1024, 256, 0, stream>>>(Qp, aD, Qf, 1);
        kg2<<<640, 256, 0, stream>>>(Qf, EHs, ELs, AH, P);
    }

    // --- finalize: recon = normalize(normalize(z @ Dp) + mean) ---
    kg1<1><<<512, 256, 0, stream>>>(P, DHs, DLs, Qp);
    kred<<<BDIM * DM / 1024, 256, 0, stream>>>(Qp, nullptr, Qf, 0);
    kfinal<<<BDIM, 256, 0, stream>>>(Qf, mean, out);
}